// Round 1
// baseline (338.963 us; speedup 1.0000x reference)
//
#include <hip/hip_runtime.h>

#define BB 512
#define SS 1024
#define TT 48
#define GG 16          // batches per WG (MFMA N)
#define CK 8           // rows per chunk
#define NSLOT 5        // LDS ring slots

typedef __attribute__((ext_vector_type(8))) short short8;
typedef __attribute__((ext_vector_type(4))) float float4v;
typedef unsigned uint2v __attribute__((ext_vector_type(2)));

// ---------- helpers ----------
__device__ __forceinline__ unsigned short f2bf(float x) {
    unsigned u = __float_as_uint(x);
    u += 0x7FFFu + ((u >> 16) & 1u);
    return (unsigned short)(u >> 16);
}
__device__ __forceinline__ unsigned pk2bf(float lo, float hi) {
#if __has_builtin(__builtin_amdgcn_cvt_pk_bf16_f32)
    typedef __bf16 bf16x2 __attribute__((ext_vector_type(2)));
    union { bf16x2 v; unsigned u; } cv;
    cv.v = __builtin_amdgcn_cvt_pk_bf16_f32(lo, hi);
    return cv.u;
#else
    return __builtin_amdgcn_perm(__float_as_uint(hi) + 0x8000u,
                                 __float_as_uint(lo) + 0x8000u, 0x07060302u);
#endif
}
__device__ __forceinline__ float bflo(unsigned u) { return __uint_as_float(u << 16); }
__device__ __forceinline__ float bfhi(unsigned u) { return __uint_as_float(u & 0xFFFF0000u); }
__device__ __forceinline__ float wave_sum(float v) {
#pragma unroll
    for (int off = 32; off >= 1; off >>= 1) v += __shfl_xor(v, off, 64);
    return v;
}
__device__ __forceinline__ int wave_sum_i(int v) {
#pragma unroll
    for (int off = 32; off >= 1; off >>= 1) v += __shfl_xor(v, off, 64);
    return v;
}
// max over lanes {i, i^16, i^32, i^48} (q-groups) — VALU permlane swaps, no LDS path.
__device__ __forceinline__ float xgrp_max(float m) {
#if __has_builtin(__builtin_amdgcn_permlane16_swap) && __has_builtin(__builtin_amdgcn_permlane32_swap)
    uint2v a = __builtin_amdgcn_permlane16_swap(__float_as_uint(m), __float_as_uint(m), false, false);
    m = fmaxf(__uint_as_float(a[0]), __uint_as_float(a[1]));
    uint2v b = __builtin_amdgcn_permlane32_swap(__float_as_uint(m), __float_as_uint(m), false, false);
    m = fmaxf(__uint_as_float(b[0]), __uint_as_float(b[1]));
#else
    m = fmaxf(m, __shfl_xor(m, 16, 64));
    m = fmaxf(m, __shfl_xor(m, 32, 64));
#endif
    return m;
}
__device__ __forceinline__ float xgrp_sum(float m) {
#if __has_builtin(__builtin_amdgcn_permlane16_swap) && __has_builtin(__builtin_amdgcn_permlane32_swap)
    uint2v a = __builtin_amdgcn_permlane16_swap(__float_as_uint(m), __float_as_uint(m), false, false);
    m = __uint_as_float(a[0]) + __uint_as_float(a[1]);
    uint2v b = __builtin_amdgcn_permlane32_swap(__float_as_uint(m), __float_as_uint(m), false, false);
    m = __uint_as_float(b[0]) + __uint_as_float(b[1]);
#else
    m += __shfl_xor(m, 16, 64);
    m += __shfl_xor(m, 32, 64);
#endif
    return m;
}

// ---------- prep: lengths + gold-path numerator ----------
__global__ __launch_bounds__(256)
void crf_numer(const float* __restrict__ em, const int* __restrict__ tags,
               const int* __restrict__ mask, const float* __restrict__ start_tr,
               const float* __restrict__ end_tr, const float* __restrict__ trans,
               float* __restrict__ numer, int* __restrict__ lenArr) {
    const int b = blockIdx.x, tid = threadIdx.x;
    const float* emb = em + (size_t)b * SS * TT;
    const int* tg = tags + (size_t)b * SS;
    const int* mk = mask + (size_t)b * SS;
    const int s0 = tid * 4;                 // 256 threads x 4 consecutive s
    const int4 t4 = *(const int4*)(tg + s0);
    const int4 m4 = *(const int4*)(mk + s0);
    const int tprev = (tid == 0) ? 0 : tg[s0 - 1];
    int cnt = (m4.x != 0) + (m4.y != 0) + (m4.z != 0) + (m4.w != 0);
    float ns = 0.f;
    if (tid > 0 && m4.x) ns += trans[tprev * TT + t4.x] + emb[(size_t)s0 * TT + t4.x];
    if (m4.y) ns += trans[t4.x * TT + t4.y] + emb[(size_t)(s0 + 1) * TT + t4.y];
    if (m4.z) ns += trans[t4.y * TT + t4.z] + emb[(size_t)(s0 + 2) * TT + t4.z];
    if (m4.w) ns += trans[t4.z * TT + t4.w] + emb[(size_t)(s0 + 3) * TT + t4.w];
    float wsum = wave_sum(ns);
    int wcnt = wave_sum_i(cnt);
    __shared__ float sf[4]; __shared__ int si[4];
    if ((tid & 63) == 0) { sf[tid >> 6] = wsum; si[tid >> 6] = wcnt; }
    __syncthreads();
    if (tid == 0) {
        float tot = sf[0] + sf[1] + sf[2] + sf[3];
        int L = si[0] + si[1] + si[2] + si[3];
        int t0 = tg[0];
        tot += start_tr[t0] + emb[t0] + end_tr[tg[L - 1]];
        numer[b] = tot;
        lenArr[b] = L;
    }
}

// ---------- main: 5 waves/WG. wave0 = MFMA consumer; waves1-4 = 2 producer teams ----------
// LDS ring entry (slot, row u, section j, entry e): e == consumer lane (q*16+n),
// bf16x2 pair = states {j*16+q*4 .. +3} of batch n. Producers use the SAME lane
// mapping (nb=lane&15, q4=lane>>4) so both read & write at entry==lane: conflict-free.
__global__ __launch_bounds__(320, 1)
void crf_fwd(const float* __restrict__ em, const float* __restrict__ start_tr,
             const float* __restrict__ end_tr, const float* __restrict__ trans,
             const int* __restrict__ lenArr, float* __restrict__ denomArr) {
    __shared__ uint2 ring[NSLOT * CK * 3 * 64];   // 61440 B

    const int tid = threadIdx.x;
    const int wave = tid >> 6, lane = tid & 63;
    const int wgbase = blockIdx.x * GG;

    if (wave == 0) {
        // ================= CONSUMER =================
        __builtin_amdgcn_s_setprio(1);        // favor the recurrence chain on its SIMD
        const int n = lane & 15, q = lane >> 4;
        const int bb = wgbase + n;

        // A[m=s_out][k-slot(s_in)] = exp(trans[s_out][s_in])
        short8 afr[3][2];
#pragma unroll
        for (int mt = 0; mt < 3; ++mt) {
            const int so = mt * 16 + n;
#pragma unroll
            for (int kt = 0; kt < 2; ++kt) {
                short8 a;
#pragma unroll
                for (int i = 0; i < 8; ++i) {
                    int si_;
                    if (kt == 0) si_ = (i < 4) ? (q * 4 + i) : (16 + q * 4 + (i - 4));
                    else         si_ = (i < 4) ? (32 + q * 4 + i) : -1;
                    a[i] = (si_ >= 0) ? (short)f2bf(__expf(trans[so * TT + si_])) : (short)0;
                }
                afr[mt][kt] = a;
            }
        }

        // init p = exp(start) * exp(em row0)  (this is state t=0)
        const float* em0 = em + (size_t)bb * SS * TT + q * 4;
        float p[3][4];
#pragma unroll
        for (int mt = 0; mt < 3; ++mt) {
            float4 v = *(const float4*)(em0 + mt * 16);
            int sb = mt * 16 + q * 4;
            p[mt][0] = __expf(start_tr[sb + 0] + v.x);
            p[mt][1] = __expf(start_tr[sb + 1] + v.y);
            p[mt][2] = __expf(start_tr[sb + 2] + v.z);
            p[mt][3] = __expf(start_tr[sb + 3] + v.w);
        }

        const int len = lenArr[bb];
        int Lmax = len;
#pragma unroll
        for (int off = 1; off < 64; off <<= 1) {
            int o = __shfl_xor(Lmax, off, 64);
            Lmax = Lmax > o ? Lmax : o;
        }
        const int P = (Lmax + 6) >> 3;   // ceil((Lmax-1)/8)

        // deferred capture: at the iteration computing state t (=1+8pp+u), p still
        // holds state t-1; capture it when len == t. One post-loop select catches
        // len == 8P+1 (includes the len==1, P==0 case).
        float dc[3][4];
#pragma unroll
        for (int mt = 0; mt < 3; ++mt)
#pragma unroll
            for (int r = 0; r < 4; ++r) dc[mt][r] = 0.f;
        float lcap = 0.f, logscale = 0.f;
        const float4v Z = {0.f, 0.f, 0.f, 0.f};

        for (int pp = -3; pp < P; ++pp) {
            if (pp >= 0) {
                const uint2* rp = &ring[(pp % NSLOT) * (CK * 3 * 64) + lane];
                uint2 c0 = rp[0], c1 = rp[64], c2v = rp[128];
#pragma unroll
                for (int u = 0; u < 8; ++u) {
                    // ---- chain head: pack B operand from p (state t-1)
                    union { short8 v; unsigned w[4]; } B0, B1;
                    B0.w[0] = pk2bf(p[0][0], p[0][1]); B0.w[1] = pk2bf(p[0][2], p[0][3]);
                    B0.w[2] = pk2bf(p[1][0], p[1][1]); B0.w[3] = pk2bf(p[1][2], p[1][3]);
                    B1.w[0] = pk2bf(p[2][0], p[2][1]); B1.w[1] = pk2bf(p[2][2], p[2][3]);
                    B1.w[2] = 0u; B1.w[3] = 0u;
                    // ---- 6 INDEPENDENT MFMAs (split-K; reassociated, no mfma->mfma dep)
                    float4v A0a = __builtin_amdgcn_mfma_f32_16x16x32_bf16(afr[0][0], B0.v, Z, 0, 0, 0);
                    float4v A1a = __builtin_amdgcn_mfma_f32_16x16x32_bf16(afr[1][0], B0.v, Z, 0, 0, 0);
                    float4v A2a = __builtin_amdgcn_mfma_f32_16x16x32_bf16(afr[2][0], B0.v, Z, 0, 0, 0);
                    float4v A0b = __builtin_amdgcn_mfma_f32_16x16x32_bf16(afr[0][1], B1.v, Z, 0, 0, 0);
                    float4v A1b = __builtin_amdgcn_mfma_f32_16x16x32_bf16(afr[1][1], B1.v, Z, 0, 0, 0);
                    float4v A2b = __builtin_amdgcn_mfma_f32_16x16x32_bf16(afr[2][1], B1.v, Z, 0, 0, 0);
                    // ---- shadow work (independent of MFMA results)
                    uint2 n0, n1, n2;
                    if (u < 7) {
                        n0 = rp[(u + 1) * 192];
                        n1 = rp[(u + 1) * 192 + 64];
                        n2 = rp[(u + 1) * 192 + 128];
                    }
                    float e00 = bflo(c0.x),  e01 = bfhi(c0.x),  e02 = bflo(c0.y),  e03 = bfhi(c0.y);
                    float e10 = bflo(c1.x),  e11 = bfhi(c1.x),  e12 = bflo(c1.y),  e13 = bfhi(c1.y);
                    float e20 = bflo(c2v.x), e21 = bfhi(c2v.x), e22 = bflo(c2v.y), e23 = bfhi(c2v.y);
                    // deferred capture of state t-1, hidden under MFMA latency
                    bool cc = (len == 8 * pp + u + 1);
#pragma unroll
                    for (int mt = 0; mt < 3; ++mt)
#pragma unroll
                        for (int r = 0; r < 4; ++r) dc[mt][r] = cc ? p[mt][r] : dc[mt][r];
                    lcap = cc ? logscale : lcap;
                    // ---- consume MFMA results: p_t = (M @ p_{t-1}) * exp(em_t)
                    p[0][0] = (A0a[0] + A0b[0]) * e00; p[0][1] = (A0a[1] + A0b[1]) * e01;
                    p[0][2] = (A0a[2] + A0b[2]) * e02; p[0][3] = (A0a[3] + A0b[3]) * e03;
                    p[1][0] = (A1a[0] + A1b[0]) * e10; p[1][1] = (A1a[1] + A1b[1]) * e11;
                    p[1][2] = (A1a[2] + A1b[2]) * e12; p[1][3] = (A1a[3] + A1b[3]) * e13;
                    p[2][0] = (A2a[0] + A2b[0]) * e20; p[2][1] = (A2a[1] + A2b[1]) * e21;
                    p[2][2] = (A2a[2] + A2b[2]) * e22; p[2][3] = (A2a[3] + A2b[3]) * e23;
                    c0 = n0; c1 = n1; c2v = n2;
                    if (u == 7) {   // renorm once per chunk (VALU-only cross-lane max)
                        float m = fmaxf(fmaxf(p[0][0], p[0][1]), fmaxf(p[0][2], p[0][3]));
                        m = fmaxf(m, fmaxf(fmaxf(p[1][0], p[1][1]), fmaxf(p[1][2], p[1][3])));
                        m = fmaxf(m, fmaxf(fmaxf(p[2][0], p[2][1]), fmaxf(p[2][2], p[2][3])));
                        m = xgrp_max(m);
                        m = fmaxf(m, 1e-30f);
                        logscale += __logf(m);
                        float rm = __builtin_amdgcn_rcpf(m);
#pragma unroll
                        for (int mt = 0; mt < 3; ++mt)
#pragma unroll
                            for (int r = 0; r < 4; ++r) p[mt][r] *= rm;
                    }
                }
            }
            __builtin_amdgcn_s_barrier();
        }
        // final deferred capture: len == 8P+1 (covers len==1 when P==0)
        {
            bool cc = (len == 8 * P + 1);
#pragma unroll
            for (int mt = 0; mt < 3; ++mt)
#pragma unroll
                for (int r = 0; r < 4; ++r) dc[mt][r] = cc ? p[mt][r] : dc[mt][r];
            lcap = cc ? logscale : lcap;
        }

        // epilogue
        float pe = 0.f;
#pragma unroll
        for (int mt = 0; mt < 3; ++mt) {
            int sb = mt * 16 + q * 4;
            pe = fmaf(dc[mt][0], __expf(end_tr[sb + 0]), pe);
            pe = fmaf(dc[mt][1], __expf(end_tr[sb + 1]), pe);
            pe = fmaf(dc[mt][2], __expf(end_tr[sb + 2]), pe);
            pe = fmaf(dc[mt][3], __expf(end_tr[sb + 3]), pe);
        }
        pe = xgrp_sum(pe);
        if (lane < 16) denomArr[bb] = lcap + __logf(pe);

    } else {
        // ================= PRODUCERS (waves 1..4, two teams) =================
        const int T = (wave - 1) >> 1;       // team parity: chunks c with (c&1)==T
        const int sub = (wave - 1) & 1;      // items i = sub*12 .. sub*12+11
        const int nb = lane & 15, q4 = lane >> 4;   // SAME mapping as consumer
        const int bb = wgbase + nb;
        const int len_v = lenArr[bb];
        int Lmax = len_v;
#pragma unroll
        for (int off = 1; off < 64; off <<= 1) {
            int o = __shfl_xor(Lmax, off, 64);
            Lmax = Lmax > o ? Lmax : o;
        }
        const int P = (Lmax + 6) >> 3;

        const float* emP = em + (size_t)bb * SS * TT + q4 * 4;
        float4 buf[12];   // single named buffer, constant indices -> registers

        for (int pp = -3; pp < P; ++pp) {
            int cv = pp + 1;                 // chunk to convert (loaded 2 periods ago)
            if (cv >= 0 && cv < P && (cv & 1) == T) {
                uint2* wp = &ring[(cv % NSLOT) * (CK * 3 * 64) + lane];
#pragma unroll
                for (int k = 0; k < 12; ++k) {
                    const int i = sub * 12 + k, u = i / 3, j = i % 3;
                    int t = 1 + 8 * cv + u;
                    bool live = t < len_v;
                    float4 v = buf[k];
                    unsigned ox = pk2bf(__expf(v.x), __expf(v.y));
                    unsigned oy = pk2bf(__expf(v.z), __expf(v.w));
                    uint2 o;
                    o.x = live ? ox : 0u;
                    o.y = live ? oy : 0u;
                    wp[u * 192 + j * 64] = o;
                }
            }
            int ci = pp + 3;                 // chunk to issue loads for (same parity)
            if (ci < P && (ci & 1) == T) {
#pragma unroll
                for (int k = 0; k < 12; ++k) {
                    const int i = sub * 12 + k, u = i / 3, j = i % 3;
                    int t = 1 + 8 * ci + u; t = t < SS ? t : SS - 1;
                    buf[k] = *(const float4*)(emP + (size_t)t * TT + j * 16);
                }
            }
            __builtin_amdgcn_s_waitcnt(0xC07F);  // lgkmcnt(0) only; vmcnt stays in flight
            __builtin_amdgcn_s_barrier();
        }
    }
}

__global__ __launch_bounds__(64)
void crf_reduce(const float* __restrict__ denom, const float* __restrict__ numer,
                float* __restrict__ out) {
    int lane = threadIdx.x;
    float s = 0.f;
    for (int i = lane; i < BB; i += 64) s += denom[i] - numer[i];
    s = wave_sum(s);
    if (lane == 0) out[0] = s * (1.0f / (float)BB);
}

extern "C" void kernel_launch(void* const* d_in, const int* in_sizes, int n_in,
                              void* d_out, int out_size, void* d_ws, size_t ws_size,
                              hipStream_t stream) {
    const float* emissions = (const float*)d_in[0];
    const int*   tags      = (const int*)d_in[1];
    const int*   mask      = (const int*)d_in[2];
    const float* start_tr  = (const float*)d_in[3];
    const float* end_tr    = (const float*)d_in[4];
    const float* trans     = (const float*)d_in[5];

    char* ws = (char*)d_ws;
    float* denom = (float*)ws;               // 512 f32
    float* numer = (float*)(ws + 2048);      // 512 f32
    int*   lenA  = (int*)(ws + 4096);        // 512 i32

    crf_numer<<<BB, 256, 0, stream>>>(emissions, tags, mask, start_tr, end_tr,
                                      trans, numer, lenA);
    crf_fwd<<<BB / GG, 320, 0, stream>>>(emissions, start_tr, end_tr, trans,
                                         lenA, denom);
    crf_reduce<<<1, 64, 0, stream>>>(denom, numer, (float*)d_out);
}